// Round 11
// baseline (252.083 us; speedup 1.0000x reference)
//
#include <hip/hip_runtime.h>
#include <hip/hip_fp16.h>

#define NCH 32          // channels
#define NB 8            // radial basis
#define NPB 8           // nodes per block (node_kernel)

typedef __attribute__((ext_vector_type(2))) _Float16 half2r;
typedef __attribute__((ext_vector_type(2))) __fp16 fp16v2;

__device__ __forceinline__ unsigned short f2h(float f) {
    return __half_as_ushort(__float2half_rn(f));
}
__device__ __forceinline__ float h2f_lo(unsigned int u) {
    half2r v = __builtin_bit_cast(half2r, u);
    return (float)v.x;
}
__device__ __forceinline__ float h2f_hi(unsigned int u) {
    half2r v = __builtin_bit_cast(half2r, u);
    return (float)v.y;
}
__device__ __forceinline__ unsigned int pack2h(float lo, float hi) {
    return (unsigned int)f2h(lo) | ((unsigned int)f2h(hi) << 16);
}
// pack 2 floats -> fp16 pair in one v_cvt_pkrtz where available
__device__ __forceinline__ unsigned int pkrtz(float lo, float hi) {
#if __has_builtin(__builtin_amdgcn_cvt_pkrtz)
    fp16v2 t = __builtin_amdgcn_cvt_pkrtz(lo, hi);
    return __builtin_bit_cast(unsigned int, t);
#else
    return pack2h(lo, hi);
#endif
}

// y = dot(packed half2 a, packed half2 b) + c   (v_dot2_f32_f16 when available)
__device__ __forceinline__ float fdot2u(unsigned int a, unsigned int b, float c) {
#if __has_builtin(__builtin_amdgcn_fdot2)
    return __builtin_amdgcn_fdot2(__builtin_bit_cast(half2r, a),
                                  __builtin_bit_cast(half2r, b), c, false);
#else
    half2r av = __builtin_bit_cast(half2r, a);
    half2r bv = __builtin_bit_cast(half2r, b);
    return c + (float)av.x * (float)bv.x + (float)av.y * (float)bv.y;
#endif
}

// y += dot(8 fp16 weights, 8 fp16 features), fp32 accumulate
__device__ __forceinline__ void acc8h(float& y, uint4 w, uint4 f) {
    y = fdot2u(w.x, f.x, y);
    y = fdot2u(w.y, f.y, y);
    y = fdot2u(w.z, f.z, y);
    y = fdot2u(w.w, f.w, y);
}
// y += dot(8 fp16 weights, 8 fp32 values)
__device__ __forceinline__ void acc8fh(float& y, uint4 w, float4 a, float4 b) {
    y += h2f_lo(w.x) * a.x + h2f_hi(w.x) * a.y + h2f_lo(w.y) * a.z + h2f_hi(w.y) * a.w
       + h2f_lo(w.z) * b.x + h2f_hi(w.z) * b.y + h2f_lo(w.w) * b.z + h2f_hi(w.w) * b.w;
}

// ---------------------------------------------------------------------------
// FUSED prep kernel. Block roles:
//   [0, TB)          : node transpose -> fp16 gather tables t0g/t1g/t2g
//   [TB, TB+56)      : wprep  (fp16 swizzled U/V/Wg table)
//   [TB+56, TB+62)   : wprep_rad (packed fp16 radial weights, channel-major)
//   [TB+62, ...)     : hist (degree histogram; independent of other roles)
// ---------------------------------------------------------------------------
__global__ __launch_bounds__(256) void prep_kernel(
    const float* __restrict__ node0, const float* __restrict__ node1,
    const float* __restrict__ node2,
    const float* __restrict__ U, const float* __restrict__ V,
    const float* __restrict__ Wg, const float* __restrict__ Wrad,
    const int* __restrict__ idx_i, int* __restrict__ cursor,
    uint2* __restrict__ t0g, uint4* __restrict__ t1g,
    unsigned short* __restrict__ t2g,
    unsigned short* __restrict__ wswz, unsigned int* __restrict__ wradp,
    int N, int E, int TB)
{
    __shared__ float s1[8 * 96];
    __shared__ float s2[8 * 288];
    const int bx = blockIdx.x;

    if (bx < TB) {
        // ---- transpose path: fp16 gather tables, 26 B per (node,channel) ----
        const int nb0 = bx * 8;
        const int remN = N - nb0;
        if (remN >= 8) {
            const float4* src1 = reinterpret_cast<const float4*>(node1 + (size_t)nb0 * 96);
            float4* d1 = reinterpret_cast<float4*>(s1);
            for (int i = threadIdx.x; i < 192; i += 256) d1[i] = src1[i];
            const float4* src2 = reinterpret_cast<const float4*>(node2 + (size_t)nb0 * 288);
            float4* d2 = reinterpret_cast<float4*>(s2);
            for (int i = threadIdx.x; i < 576; i += 256) d2[i] = src2[i];
        } else {
            const int tot1 = remN * 96;
            for (int i = threadIdx.x; i < 768; i += 256)
                s1[i] = (i < tot1) ? node1[(size_t)nb0 * 96 + i] : 0.f;
            const int tot2 = remN * 288;
            for (int i = threadIdx.x; i < 2304; i += 256)
                s2[i] = (i < tot2) ? node2[(size_t)nb0 * 288 + i] : 0.f;
        }
        __syncthreads();

        const int g = threadIdx.x >> 5;
        const int c = threadIdx.x & 31;
        const int n = nb0 + g;
        if (n >= N) return;

        float G0 = node0[(size_t)n * 32 + c];
        float G1[3];
        #pragma unroll
        for (int a = 0; a < 3; ++a) G1[a] = s1[g * 96 + c * 3 + a];   // stride 3: conflict-free
        float G2[9];
        #pragma unroll
        for (int k = 0; k < 9; ++k) G2[k] = s2[g * 288 + c * 9 + k];  // stride 9: conflict-free

        const size_t b = ((size_t)n << 5) + c;
        uint2 P0;
        P0.x = pack2h(G0, G1[0]);
        P0.y = pack2h(G1[1], G1[2]);
        uint4 P1;
        P1.x = pack2h(G2[0], G2[1]);
        P1.y = pack2h(G2[2], G2[3]);
        P1.z = pack2h(G2[4], G2[5]);
        P1.w = pack2h(G2[6], G2[7]);
        t0g[b] = P0;
        t1g[b] = P1;
        t2g[b] = f2h(G2[8]);
        return;
    }

    const int r = bx - TB;
    if (r < 56) {
        // ---- wprep: wswz[m*1024 + (c>>3)*256 + d*8 + (c&7)] = fp16(W_m[c][d]) ----
        int idx = r * 256 + threadIdx.x;
        if (idx >= 14 * 1024) return;
        int m = idx >> 10, rr = idx & 1023;
        int c = rr >> 5, d = rr & 31;
        float v;
        if (m < 3)       v = U[m * 1024 + c * 32 + d];
        else if (m < 11) v = V[(m - 3) * 1024 + c * 32 + d];
        else             v = Wg[(m - 11) * 1024 + c * 32 + d];
        wswz[m * 1024 + (c >> 3) * 256 + d * 8 + (c & 7)] = f2h(v);
        return;
    }
    if (r < 62) {
        // ---- wprep_rad: wradp[c*44 + p*4 + bb], pre-scaled 1/16, channel-major ----
        int idx = (r - 56) * 256 + threadIdx.x;
        if (idx >= 11 * 4 * 32) return;
        int c = idx & 31, bb = (idx >> 5) & 3, p = idx >> 7;
        float lo = Wrad[p * 256 + (2 * bb) * 32 + c] * (1.0f / 16.0f);
        float hi = Wrad[p * 256 + (2 * bb + 1) * 32 + c] * (1.0f / 16.0f);
        wradp[c * 44 + p * 4 + bb] = pack2h(lo, hi);
        return;
    }
    {
        // ---- hist: independent of the roles above (needs only zeroed cursor) ----
        int e = (r - 62) * 256 + threadIdx.x;
        if (e < E) atomicAdd(&cursor[idx_i[e]], 1);
    }
}

// ---------------------------------------------------------------------------
// CSR scan, 2 dispatches: per-block reduce, then write (each write-block
// computes its own base by prefixing <=64 block sums).
// ---------------------------------------------------------------------------
__global__ __launch_bounds__(256) void scan_reduce_kernel(
    const int* __restrict__ counts, int* __restrict__ blocksums, int N)
{
    const int tid = threadIdx.x;
    const int base = blockIdx.x * 1024;
    int v = 0;
    #pragma unroll
    for (int k = 0; k < 4; ++k) {
        int i = base + tid * 4 + k;
        if (i < N) v += counts[i];
    }
    #pragma unroll
    for (int off = 1; off < 64; off <<= 1) v += __shfl_xor(v, off, 64);
    __shared__ int wsum[4];
    if ((tid & 63) == 0) wsum[tid >> 6] = v;
    __syncthreads();
    if (tid == 0) blocksums[blockIdx.x] = wsum[0] + wsum[1] + wsum[2] + wsum[3];
}

__global__ __launch_bounds__(256) void scan_write_kernel(
    int* __restrict__ cursor, const int* __restrict__ blocksums,
    int* __restrict__ offsets, int nb, int N)
{
    const int tid = threadIdx.x;
    const int i0 = blockIdx.x * 1024 + tid * 4;
    int v[4]; int lsum = 0;
    #pragma unroll
    for (int k = 0; k < 4; ++k) {
        int i = i0 + k;
        v[k] = (i < N) ? cursor[i] : 0;
        lsum += v[k];
    }
    int incl = lsum;
    #pragma unroll
    for (int off = 1; off < 64; off <<= 1) {
        int t = __shfl_up(incl, off, 64);
        if ((tid & 63) >= off) incl += t;
    }
    __shared__ int wsum[4];
    if ((tid & 63) == 63) wsum[tid >> 6] = incl;
    __syncthreads();
    int add = 0;
    for (int b = 0; b < blockIdx.x; ++b) add += blocksums[b];
    for (int w = 0; w < (tid >> 6); ++w) add += wsum[w];
    int run = add + incl - lsum;
    #pragma unroll
    for (int k = 0; k < 4; ++k) {
        int i = i0 + k;
        if (i < N) { offsets[i] = run; cursor[i] = run; run += v[k]; }
    }
    if (blockIdx.x == 0 && tid == 0) {
        int tot = 0;
        for (int b = 0; b < nb; ++b) tot += blocksums[b];
        offsets[N] = tot;   // = E
    }
}

// scatter into CSR order; 12 B/edge (halved scattered-write footprint):
//   me[slot] = uint3{ hx|hy (fp16), hz | (j<<16), dist (fp32 bits) }
// RBF evaluation moved into aggregate (reconstructed from dist).
__global__ __launch_bounds__(256) void scatter_meta_kernel(
    const int* __restrict__ idx_i, const int* __restrict__ idx_j,
    const float* __restrict__ rij, int* __restrict__ cursor,
    uint3* __restrict__ me, int E)
{
    int e = blockIdx.x * 256 + threadIdx.x;
    if (e >= E) return;
    float rx = rij[3 * e + 0], ry = rij[3 * e + 1], rz = rij[3 * e + 2];
    float sq = rx * rx + ry * ry + rz * rz + 1e-12f;
    float inv = rsqrtf(sq);
    float dist = sq * inv;
    const int i = idx_i[e];
    const unsigned int j = (unsigned int)idx_j[e];
    int slot = atomicAdd(&cursor[i], 1);
    uint3 rec;
    rec.x = pack2h(rx * inv, ry * inv);
    rec.y = (unsigned int)f2h(rz * inv) | (j << 16);
    rec.z = __float_as_uint(dist);
    me[slot] = rec;
}

// ---------------------------------------------------------------------------
// Per-edge message math. RBF reconstructed from dist via Gaussian
// factorization: rbf[b] = fc*exp(-(2d-1)^2) * q^b * exp(-4w^2 b^2),
// q = exp(4w(2d-1)), w = 4.5/7. d clamped to 5 (fc=0 there -> rbf=0, exact).
// rbc[b] = exp(-4w^2(2b+1)) precomputed per thread (prologue).
// ---------------------------------------------------------------------------
__device__ __forceinline__ void edge_compute(
    uint2 P0, uint4 P1, unsigned short g28, uint3 ME,
    const uint4 wrq[11], const float rbc[7],
    float& A0, float (&A1)[3], float (&A2)[9])
{
    const float h0 = h2f_lo(ME.x), h1 = h2f_hi(ME.x), h2 = h2f_lo(ME.y);
    const float d  = __uint_as_float(ME.z);

    // radial basis from dist
    const float dc = fminf(d, 5.0f);
    const float fc = 0.5f * (__cosf(0.6283185307f * dc) + 1.0f);  // cos(pi*d/5)
    const float u  = 2.0f * dc - 1.0f;
    float f[8];
    f[0] = fc * __expf(-u * u);
    const float q = __expf(2.5714285714f * u);                    // 4w*u
    #pragma unroll
    for (int b = 0; b < 7; ++b) f[b + 1] = f[b] * (q * rbc[b]);
    const unsigned int rb01 = pkrtz(f[0], f[1]);
    const unsigned int rb23 = pkrtz(f[2], f[3]);
    const unsigned int rb45 = pkrtz(f[4], f[5]);
    const unsigned int rb67 = pkrtz(f[6], f[7]);

    float w[11];
    #pragma unroll
    for (int p = 0; p < 11; ++p)
        w[p] = fdot2u(rb01, wrq[p].x,
               fdot2u(rb23, wrq[p].y,
               fdot2u(rb45, wrq[p].z,
               fdot2u(rb67, wrq[p].w, 0.0f))));

    const float G0 = h2f_lo(P0.x);
    float G1[3];
    G1[0] = h2f_hi(P0.x); G1[1] = h2f_lo(P0.y); G1[2] = h2f_hi(P0.y);
    float G2[9];
    G2[0] = h2f_lo(P1.x); G2[1] = h2f_hi(P1.x);
    G2[2] = h2f_lo(P1.y); G2[3] = h2f_hi(P1.y);
    G2[4] = h2f_lo(P1.z); G2[5] = h2f_hi(P1.z);
    G2[6] = h2f_lo(P1.w); G2[7] = h2f_hi(P1.w);
    G2[8] = __half2float(__ushort_as_half(g28));

    const float hh[3] = {h0, h1, h2};
    const float s1 = G1[0] * h0 + G1[1] * h1 + G1[2] * h2;
    float tt[3];
    #pragma unroll
    for (int a = 0; a < 3; ++a)
        tt[a] = G2[a * 3 + 0] * h0 + G2[a * 3 + 1] * h1 + G2[a * 3 + 2] * h2;
    const float s2 = tt[0] * h0 + tt[1] * h1 + tt[2] * h2;

    A0 += G0 * w[0] + s1 * w[4] + s2 * w[9];
    #pragma unroll
    for (int a = 0; a < 3; ++a)
        A1[a] += (G0 * w[1] + s1 * w[6]) * hh[a] + G1[a] * w[3] + tt[a] * w[8];
    #pragma unroll
    for (int a = 0; a < 3; ++a) {
        float pre = G0 * w[2] * hh[a] + G1[a] * w[5] + tt[a] * w[10];
        #pragma unroll
        for (int b = 0; b < 3; ++b)
            A2[a * 3 + b] += pre * hh[b] + G2[a * 3 + b] * w[7];
    }
}

// ---------------------------------------------------------------------------
// Aggregate kernel: v3 structure (proven 74.5 us), meta slimmed to one 12 B
// uint3 record per edge (j embedded; rbf from dist). One WAVE64 per node,
// lane=(side<<5)|c, 2 slots/side = 4 edges in flight.
// ---------------------------------------------------------------------------
__global__ __launch_bounds__(256) void aggregate_kernel(
    const uint2* __restrict__ t0g, const uint4* __restrict__ t1g,
    const unsigned short* __restrict__ t2g, const unsigned int* __restrict__ wradp,
    const uint3* __restrict__ me, const int* __restrict__ offsets,
    float* __restrict__ a0, float* __restrict__ a1, float* __restrict__ a2,
    int N)
{
    const int lane = threadIdx.x & 63;
    const int c = lane & 31;
    const int side = lane >> 5;
    const int n = blockIdx.x * 4 + (threadIdx.x >> 6);
    if (n >= N) return;

    // my channel's radial weights: 11 x dwordx4 (contiguous per lane)
    uint4 wrq[11];
    {
        const uint4* wrv = reinterpret_cast<const uint4*>(wradp) + c * 11;
        #pragma unroll
        for (int p = 0; p < 11; ++p) wrq[p] = wrv[p];
    }
    // rbf chain constants: exp(-4w^2 (2b+1)), 4w^2 = 81/49
    float rbc[7];
    #pragma unroll
    for (int b = 0; b < 7; ++b) rbc[b] = __expf(-1.6530612245f * (float)(2 * b + 1));

    const int beg = offsets[n], end = offsets[n + 1];
    const int deg = end - beg;

    float A0 = 0.f;
    float A1[3] = {0.f, 0.f, 0.f};
    float A2[9] = {0.f, 0.f, 0.f, 0.f, 0.f, 0.f, 0.f, 0.f, 0.f};

    if (deg > 0) {
        const int last = end - 1;
        int eA = beg + side;     // slot A edges: beg+side, +4, +8, ...
        int eB = eA + 2;         // slot B edges: beg+side+2, +6, ...

        uint3 MEA, MEB, MAn, MBn;
        uint2 P0A, P0B; uint4 P1A, P1B; unsigned short s2A, s2B;
        {
            MEA = me[min(eA, last)];
            const size_t b = ((size_t)(MEA.y >> 16) << 5) + c;
            P0A = t0g[b]; P1A = t1g[b]; s2A = t2g[b];
            MAn = me[min(eA + 4, last)];
        }
        {
            MEB = me[min(eB, last)];
            const size_t b = ((size_t)(MEB.y >> 16) << 5) + c;
            P0B = t0g[b]; P1B = t1g[b]; s2B = t2g[b];
            MBn = me[min(eB + 4, last)];
        }

        const int M = (deg + 3) >> 2;

#define SLOT_STEP(P0s, P1s, s2s, MEs, MNs, eS)                              \
        {                                                                   \
            const uint2 P0 = P0s; const uint4 P1 = P1s;                     \
            const unsigned short g28 = s2s;                                 \
            const uint3 MEc = MEs;                                          \
            const bool v = (eS < end);                                      \
            const int eSn = eS + 4;                                         \
            {                                                               \
                const size_t b = ((size_t)(MNs.y >> 16) << 5) + c;          \
                P0s = t0g[b]; P1s = t1g[b]; s2s = t2g[b];                   \
            }                                                               \
            MEs = MNs;                                                      \
            MNs = me[min(eSn + 4, last)];                                   \
            if (v) edge_compute(P0, P1, g28, MEc, wrq, rbc, A0, A1, A2);    \
            eS = eSn;                                                       \
        }

        for (int m = 0; m < M; ++m) {
            SLOT_STEP(P0A, P1A, s2A, MEA, MAn, eA)
            SLOT_STEP(P0B, P1B, s2B, MEB, MBn, eB)
        }
#undef SLOT_STEP
    }

    // combine even/odd partial sums across the two wave halves
    A0 += __shfl_xor(A0, 32, 64);
    #pragma unroll
    for (int a = 0; a < 3; ++a) A1[a] += __shfl_xor(A1[a], 32, 64);
    #pragma unroll
    for (int k = 0; k < 9; ++k) A2[k] += __shfl_xor(A2[k], 32, 64);

    if (side == 0) {
        a0[n * 32 + c] = A0;
        #pragma unroll
        for (int a = 0; a < 3; ++a) a1[n * 96 + a * 32 + c] = A1[a];
        #pragma unroll
        for (int k = 0; k < 9; ++k) a2[n * 288 + k * 32 + c] = A2[k];
    }
}

// ---------------------------------------------------------------------------
// Node kernel (round-7 proven form): weights read DIRECTLY from global
// (28.7 KB hot set shared via L1/L2); LDS holds only the per-block feature
// tensor -> 26.1 KB -> 6 blocks/CU.
// ---------------------------------------------------------------------------
__global__ __launch_bounds__(256) void node_kernel(
    const float* __restrict__ node0, const float* __restrict__ node1,
    const float* __restrict__ node2, const unsigned short* __restrict__ wswz,
    float* __restrict__ out0, float* __restrict__ out1, float* __restrict__ out2,
    int N)
{
    __shared__ alignas(16) unsigned short feat[NPB * 49 * 32]; // 25.1 KB fp16
    __shared__ alignas(16) float y0s[NPB][32];                 // 1 KB

    const uint4* __restrict__ W4 = reinterpret_cast<const uint4*>(wswz); // m*128 + q*32 + d

    const int g = threadIdx.x >> 5;
    const int lane = threadIdx.x & 31;
    const int n = blockIdx.x * NPB + g;
    const bool active = (n < N);

    if (active) {
        const int c = lane;
        float A0 = out0[n * 32 + c];
        float A1[3], A2[9];
        #pragma unroll
        for (int a = 0; a < 3; ++a) A1[a] = out1[n * 96 + a * 32 + c];   // transposed
        #pragma unroll
        for (int k = 0; k < 9; ++k) A2[k] = out2[n * 288 + k * 32 + c];  // transposed

        unsigned short* F = &feat[g * 49 * 32];
        F[0 * 32 + c] = f2h(A0);
        F[1 * 32 + c] = f2h(A0 * A0);
        F[2 * 32 + c] = f2h(A1[0] * A1[0] + A1[1] * A1[1] + A1[2] * A1[2]);
        float n2 = 0.f;
        #pragma unroll
        for (int k = 0; k < 9; ++k) n2 += A2[k] * A2[k];
        F[3 * 32 + c] = f2h(n2);
        #pragma unroll
        for (int a = 0; a < 3; ++a) {
            F[(4 + a) * 32 + c] = f2h(A1[a]);
            F[(7 + a) * 32 + c] = f2h(A0 * A1[a]);
        }
        #pragma unroll
        for (int b = 0; b < 3; ++b) {  // B5[b] = sum_a a1[a]*a2[a,b]
            float s = A1[0] * A2[0 * 3 + b] + A1[1] * A2[1 * 3 + b] + A1[2] * A2[2 * 3 + b];
            F[(10 + b) * 32 + c] = f2h(s);
        }
        #pragma unroll
        for (int k = 0; k < 9; ++k) {
            F[(13 + k) * 32 + c] = f2h(A2[k]);
            F[(22 + k) * 32 + c] = f2h(A0 * A2[k]);
        }
        #pragma unroll
        for (int a = 0; a < 3; ++a)
            #pragma unroll
            for (int b = 0; b < 3; ++b)
                F[(31 + a * 3 + b) * 32 + c] = f2h(A1[a] * A1[b]);
        #pragma unroll
        for (int a = 0; a < 3; ++a)
            #pragma unroll
            for (int dd = 0; dd < 3; ++dd) { // B7[a,d] = sum_b a2[a,b]*a2[b,d]
                float s = A2[a * 3 + 0] * A2[0 * 3 + dd] + A2[a * 3 + 1] * A2[1 * 3 + dd]
                        + A2[a * 3 + 2] * A2[2 * 3 + dd];
                F[(40 + a * 3 + dd) * 32 + c] = f2h(s);
            }
    }
    __syncthreads();

    const int d = lane;
    float y0v = 0.f;
    float y1v[3] = {0.f, 0.f, 0.f};
    float y2v[9] = {0.f, 0.f, 0.f, 0.f, 0.f, 0.f, 0.f, 0.f, 0.f};

    if (active) {
        const uint4* F4 = reinterpret_cast<const uint4*>(&feat[g * 49 * 32]); // f*4 + q
        for (int q = 0; q < 4; ++q) {
            const int q32d = q * 32 + d;
            acc8h(y0v, W4[0 * 128 + q32d], F4[0 * 4 + q]);
            acc8h(y0v, W4[3 * 128 + q32d], F4[1 * 4 + q]);
            acc8h(y0v, W4[6 * 128 + q32d], F4[2 * 4 + q]);
            acc8h(y0v, W4[9 * 128 + q32d], F4[3 * 4 + q]);
            uint4 wU1 = W4[1 * 128 + q32d];
            uint4 wV1 = W4[4 * 128 + q32d];
            uint4 wV5 = W4[8 * 128 + q32d];
            #pragma unroll
            for (int a = 0; a < 3; ++a) {
                acc8h(y1v[a], wU1, F4[(4 + a) * 4 + q]);
                acc8h(y1v[a], wV1, F4[(7 + a) * 4 + q]);
                acc8h(y1v[a], wV5, F4[(10 + a) * 4 + q]);
            }
            uint4 wU2 = W4[2 * 128 + q32d];
            uint4 wV2 = W4[5 * 128 + q32d];
            uint4 wV4 = W4[7 * 128 + q32d];
            uint4 wV7 = W4[10 * 128 + q32d];
            #pragma unroll
            for (int k = 0; k < 9; ++k) {
                acc8h(y2v[k], wU2, F4[(13 + k) * 4 + q]);
                acc8h(y2v[k], wV2, F4[(22 + k) * 4 + q]);
                acc8h(y2v[k], wV4, F4[(31 + k) * 4 + q]);
                acc8h(y2v[k], wV7, F4[(40 + k) * 4 + q]);
            }
        }
        y0s[g][d] = y0v;
    }
    __syncthreads();

    if (!active) return;

    float t0 = 0.f, t1 = 0.f, t2 = 0.f;
    {
        const float4* Y4 = reinterpret_cast<const float4*>(y0s[g]);
        #pragma unroll
        for (int q = 0; q < 4; ++q) {
            const int q32d = q * 32 + d;
            float4 ya = Y4[2 * q], yb = Y4[2 * q + 1];
            acc8fh(t0, W4[11 * 128 + q32d], ya, yb);
            acc8fh(t1, W4[12 * 128 + q32d], ya, yb);
            acc8fh(t2, W4[13 * 128 + q32d], ya, yb);
        }
    }
    float s0 = t0 / (1.0f + __expf(-t0));
    float s1 = t1 / (1.0f + __expf(-t1));
    float s2 = t2 / (1.0f + __expf(-t2));

    out0[n * 32 + d] = node0[n * 32 + d] + s0;
    #pragma unroll
    for (int a = 0; a < 3; ++a)
        out1[n * 96 + d * 3 + a] = node1[n * 96 + d * 3 + a] + y1v[a] * s1;
    #pragma unroll
    for (int k = 0; k < 9; ++k)
        out2[n * 288 + d * 9 + k] = node2[n * 288 + d * 9 + k] + y2v[k] * s2;
}

extern "C" void kernel_launch(void* const* d_in, const int* in_sizes, int n_in,
                              void* d_out, int out_size, void* d_ws, size_t ws_size,
                              hipStream_t stream)
{
    const float* node0 = (const float*)d_in[0];
    const float* node1 = (const float*)d_in[1];
    const float* node2 = (const float*)d_in[2];
    const float* rij   = (const float*)d_in[3];
    const float* Wrad  = (const float*)d_in[4];
    const float* U     = (const float*)d_in[5];
    const float* V     = (const float*)d_in[6];
    const float* Wg    = (const float*)d_in[7];
    const int* idx_i   = (const int*)d_in[8];
    const int* idx_j   = (const int*)d_in[9];

    const int N = in_sizes[0] / 32;
    const int E = in_sizes[3] / 3;

    float* out0 = (float*)d_out;
    float* out1 = out0 + (size_t)N * 32;
    float* out2 = out1 + (size_t)N * 96;

    // workspace carve-up (64B aligned regions)
    size_t off = 0;
    auto walloc = [&](size_t bytes) -> void* {
        off = (off + 63) & ~(size_t)63;
        void* p = (char*)d_ws + off;
        off += bytes;
        return p;
    };
    int*    cursor    = (int*)   walloc((size_t)N * 4);
    int*    offsets   = (int*)   walloc((size_t)(N + 1) * 4);
    int*    blocksums = (int*)   walloc(64 * 4);
    uint3*  me        = (uint3*) walloc((size_t)E * sizeof(uint3));        // 50 MB
    uint2*  t0g       = (uint2*) walloc((size_t)N * 32 * sizeof(uint2));   // 5.1 MB
    uint4*  t1g       = (uint4*) walloc((size_t)N * 32 * sizeof(uint4));   // 10.2 MB
    unsigned short* t2g = (unsigned short*)walloc((size_t)N * 32 * 2);     // 1.3 MB
    unsigned short* wswz = (unsigned short*)walloc(14 * 1024 * 2);
    unsigned int*  wradp = (unsigned int*)walloc(11 * 4 * 32 * 4);
    (void)ws_size;

    const int nb = (N + 1023) / 1024;
    const int TB = (N + 7) / 8;
    const int HB = (E + 255) / 256;

    hipMemsetAsync(cursor, 0, (size_t)N * sizeof(int), stream);

    prep_kernel<<<dim3(TB + 62 + HB), dim3(256), 0, stream>>>(
        node0, node1, node2, U, V, Wg, Wrad, idx_i, cursor,
        t0g, t1g, t2g, wswz, wradp, N, E, TB);
    scan_reduce_kernel<<<dim3(nb), dim3(256), 0, stream>>>(cursor, blocksums, N);
    scan_write_kernel<<<dim3(nb), dim3(256), 0, stream>>>(
        cursor, blocksums, offsets, nb, N);
    scatter_meta_kernel<<<dim3((E + 255) / 256), dim3(256), 0, stream>>>(
        idx_i, idx_j, rij, cursor, me, E);

    aggregate_kernel<<<dim3((N + 3) / 4), dim3(256), 0, stream>>>(
        t0g, t1g, t2g, wradp, me, offsets, out0, out1, out2, N);

    node_kernel<<<dim3((N + NPB - 1) / NPB), dim3(256), 0, stream>>>(
        node0, node1, node2, wswz, out0, out1, out2, N);
}

// Round 12
// 249.039 us; speedup vs baseline: 1.0122x; 1.0122x over previous
//
#include <hip/hip_runtime.h>
#include <hip/hip_fp16.h>

#define NCH 32          // channels
#define NB 8            // radial basis
#define NPB 8           // nodes per block (node_kernel)

typedef __attribute__((ext_vector_type(2))) _Float16 half2r;

__device__ __forceinline__ unsigned short f2h(float f) {
    return __half_as_ushort(__float2half_rn(f));
}
__device__ __forceinline__ float h2f_lo(unsigned int u) {
    half2r v = __builtin_bit_cast(half2r, u);
    return (float)v.x;
}
__device__ __forceinline__ float h2f_hi(unsigned int u) {
    half2r v = __builtin_bit_cast(half2r, u);
    return (float)v.y;
}
__device__ __forceinline__ unsigned int pack2h(float lo, float hi) {
    return (unsigned int)f2h(lo) | ((unsigned int)f2h(hi) << 16);
}

// y = dot(packed half2 a, packed half2 b) + c   (v_dot2_f32_f16 when available)
__device__ __forceinline__ float fdot2u(unsigned int a, unsigned int b, float c) {
#if __has_builtin(__builtin_amdgcn_fdot2)
    return __builtin_amdgcn_fdot2(__builtin_bit_cast(half2r, a),
                                  __builtin_bit_cast(half2r, b), c, false);
#else
    half2r av = __builtin_bit_cast(half2r, a);
    half2r bv = __builtin_bit_cast(half2r, b);
    return c + (float)av.x * (float)bv.x + (float)av.y * (float)bv.y;
#endif
}

// y += dot(8 fp16 weights, 8 fp16 features), fp32 accumulate
__device__ __forceinline__ void acc8h(float& y, uint4 w, uint4 f) {
    y = fdot2u(w.x, f.x, y);
    y = fdot2u(w.y, f.y, y);
    y = fdot2u(w.z, f.z, y);
    y = fdot2u(w.w, f.w, y);
}
// y += dot(8 fp16 weights, 8 fp32 values)
__device__ __forceinline__ void acc8fh(float& y, uint4 w, float4 a, float4 b) {
    y += h2f_lo(w.x) * a.x + h2f_hi(w.x) * a.y + h2f_lo(w.y) * a.z + h2f_hi(w.y) * a.w
       + h2f_lo(w.z) * b.x + h2f_hi(w.z) * b.y + h2f_lo(w.w) * b.z + h2f_hi(w.w) * b.w;
}

// ---------------------------------------------------------------------------
// FUSED prep kernel. Block roles:
//   [0, TB)          : node transpose -> fp16 gather tables t0g/t1g/t2g
//   [TB, TB+56)      : wprep  (fp16 swizzled U/V/Wg table)
//   [TB+56, TB+62)   : wprep_rad (packed fp16 radial weights, channel-major)
//   [TB+62, ...)     : hist (degree histogram; independent of other roles)
// ---------------------------------------------------------------------------
__global__ __launch_bounds__(256) void prep_kernel(
    const float* __restrict__ node0, const float* __restrict__ node1,
    const float* __restrict__ node2,
    const float* __restrict__ U, const float* __restrict__ V,
    const float* __restrict__ Wg, const float* __restrict__ Wrad,
    const int* __restrict__ idx_i, int* __restrict__ cursor,
    uint2* __restrict__ t0g, uint4* __restrict__ t1g,
    unsigned short* __restrict__ t2g,
    unsigned short* __restrict__ wswz, unsigned int* __restrict__ wradp,
    int N, int E, int TB)
{
    __shared__ float s1[8 * 96];
    __shared__ float s2[8 * 288];
    const int bx = blockIdx.x;

    if (bx < TB) {
        // ---- transpose path: fp16 gather tables, 26 B per (node,channel) ----
        const int nb0 = bx * 8;
        const int remN = N - nb0;
        if (remN >= 8) {
            const float4* src1 = reinterpret_cast<const float4*>(node1 + (size_t)nb0 * 96);
            float4* d1 = reinterpret_cast<float4*>(s1);
            for (int i = threadIdx.x; i < 192; i += 256) d1[i] = src1[i];
            const float4* src2 = reinterpret_cast<const float4*>(node2 + (size_t)nb0 * 288);
            float4* d2 = reinterpret_cast<float4*>(s2);
            for (int i = threadIdx.x; i < 576; i += 256) d2[i] = src2[i];
        } else {
            const int tot1 = remN * 96;
            for (int i = threadIdx.x; i < 768; i += 256)
                s1[i] = (i < tot1) ? node1[(size_t)nb0 * 96 + i] : 0.f;
            const int tot2 = remN * 288;
            for (int i = threadIdx.x; i < 2304; i += 256)
                s2[i] = (i < tot2) ? node2[(size_t)nb0 * 288 + i] : 0.f;
        }
        __syncthreads();

        const int g = threadIdx.x >> 5;
        const int c = threadIdx.x & 31;
        const int n = nb0 + g;
        if (n >= N) return;

        float G0 = node0[(size_t)n * 32 + c];
        float G1[3];
        #pragma unroll
        for (int a = 0; a < 3; ++a) G1[a] = s1[g * 96 + c * 3 + a];   // stride 3: conflict-free
        float G2[9];
        #pragma unroll
        for (int k = 0; k < 9; ++k) G2[k] = s2[g * 288 + c * 9 + k];  // stride 9: conflict-free

        const size_t b = ((size_t)n << 5) + c;
        uint2 P0;
        P0.x = pack2h(G0, G1[0]);
        P0.y = pack2h(G1[1], G1[2]);
        uint4 P1;
        P1.x = pack2h(G2[0], G2[1]);
        P1.y = pack2h(G2[2], G2[3]);
        P1.z = pack2h(G2[4], G2[5]);
        P1.w = pack2h(G2[6], G2[7]);
        t0g[b] = P0;
        t1g[b] = P1;
        t2g[b] = f2h(G2[8]);
        return;
    }

    const int r = bx - TB;
    if (r < 56) {
        // ---- wprep: wswz[m*1024 + (c>>3)*256 + d*8 + (c&7)] = fp16(W_m[c][d]) ----
        int idx = r * 256 + threadIdx.x;
        if (idx >= 14 * 1024) return;
        int m = idx >> 10, rr = idx & 1023;
        int c = rr >> 5, d = rr & 31;
        float v;
        if (m < 3)       v = U[m * 1024 + c * 32 + d];
        else if (m < 11) v = V[(m - 3) * 1024 + c * 32 + d];
        else             v = Wg[(m - 11) * 1024 + c * 32 + d];
        wswz[m * 1024 + (c >> 3) * 256 + d * 8 + (c & 7)] = f2h(v);
        return;
    }
    if (r < 62) {
        // ---- wprep_rad: wradp[c*44 + p*4 + bb], pre-scaled 1/16, channel-major ----
        int idx = (r - 56) * 256 + threadIdx.x;
        if (idx >= 11 * 4 * 32) return;
        int c = idx & 31, bb = (idx >> 5) & 3, p = idx >> 7;
        float lo = Wrad[p * 256 + (2 * bb) * 32 + c] * (1.0f / 16.0f);
        float hi = Wrad[p * 256 + (2 * bb + 1) * 32 + c] * (1.0f / 16.0f);
        wradp[c * 44 + p * 4 + bb] = pack2h(lo, hi);
        return;
    }
    {
        // ---- hist: independent of the roles above (needs only zeroed cursor) ----
        int e = (r - 62) * 256 + threadIdx.x;
        if (e < E) atomicAdd(&cursor[idx_i[e]], 1);
    }
}

// ---------------------------------------------------------------------------
// CSR scan: 3-stage shfl scan (proven)
// ---------------------------------------------------------------------------
__global__ __launch_bounds__(256) void scan_reduce_kernel(
    const int* __restrict__ counts, int* __restrict__ blocksums, int N)
{
    const int tid = threadIdx.x;
    const int base = blockIdx.x * 1024;
    int v = 0;
    #pragma unroll
    for (int k = 0; k < 4; ++k) {
        int i = base + tid * 4 + k;
        if (i < N) v += counts[i];
    }
    #pragma unroll
    for (int off = 1; off < 64; off <<= 1) v += __shfl_xor(v, off, 64);
    __shared__ int wsum[4];
    if ((tid & 63) == 0) wsum[tid >> 6] = v;
    __syncthreads();
    if (tid == 0) blocksums[blockIdx.x] = wsum[0] + wsum[1] + wsum[2] + wsum[3];
}

__global__ void scan_top_kernel(
    const int* __restrict__ blocksums, int* __restrict__ bases,
    int* __restrict__ offsets, int nb, int N)
{
    int l = threadIdx.x;
    int v = (l < nb) ? blocksums[l] : 0;
    int incl = v;
    #pragma unroll
    for (int off = 1; off < 64; off <<= 1) {
        int t = __shfl_up(incl, off, 64);
        if (l >= off) incl += t;
    }
    if (l < nb) bases[l] = incl - v;
    if (l == nb - 1) offsets[N] = incl;   // total = E
}

__global__ __launch_bounds__(256) void scan_write_kernel(
    int* __restrict__ cursor, const int* __restrict__ bases,
    int* __restrict__ offsets, int N)
{
    const int tid = threadIdx.x;
    const int i0 = blockIdx.x * 1024 + tid * 4;
    int v[4]; int lsum = 0;
    #pragma unroll
    for (int k = 0; k < 4; ++k) {
        int i = i0 + k;
        v[k] = (i < N) ? cursor[i] : 0;
        lsum += v[k];
    }
    int incl = lsum;
    #pragma unroll
    for (int off = 1; off < 64; off <<= 1) {
        int t = __shfl_up(incl, off, 64);
        if ((tid & 63) >= off) incl += t;
    }
    __shared__ int wsum[4];
    if ((tid & 63) == 63) wsum[tid >> 6] = incl;
    __syncthreads();
    int add = bases[blockIdx.x];
    for (int w = 0; w < (tid >> 6); ++w) add += wsum[w];
    int run = add + incl - lsum;
    #pragma unroll
    for (int k = 0; k < 4; ++k) {
        int i = i0 + k;
        if (i < N) { offsets[i] = run; cursor[i] = run; run += v[k]; }
    }
}

// scatter into CSR order; 24 B/edge, j embedded (N < 2^15 so j fits 16 bits):
//   mh[slot] = uint2{ hx|hy , hz | (j<<16) }     (8 B)
//   mr[slot] = uint4{ rb01, rb23, rb45, rb67 }   (16 B)
__global__ __launch_bounds__(256) void scatter_meta_kernel(
    const int* __restrict__ idx_i, const int* __restrict__ idx_j,
    const float* __restrict__ rij, int* __restrict__ cursor,
    uint2* __restrict__ mh, uint4* __restrict__ mr, int E)
{
    int e = blockIdx.x * 256 + threadIdx.x;
    if (e >= E) return;
    float rx = rij[3 * e + 0], ry = rij[3 * e + 1], rz = rij[3 * e + 2];
    float sq = rx * rx + ry * ry + rz * rz + 1e-12f;
    float inv = rsqrtf(sq);
    float dist = sq * inv;
    float tcl = fminf(dist * 0.2f, 1.0f);
    float fc = 0.5f * (__cosf(3.14159265358979f * tcl) + 1.0f);
    float rbf[NB];
    #pragma unroll
    for (int b = 0; b < NB; ++b) {
        float dd = dist - (0.5f + (float)b * (4.5f / 7.0f)); // linspace(0.5,5,8)
        rbf[b] = __expf(-4.0f * dd * dd) * fc;
    }
    const int i = idx_i[e];
    const unsigned int j = (unsigned int)idx_j[e];
    int slot = atomicAdd(&cursor[i], 1);
    mh[slot] = make_uint2(pack2h(rx * inv, ry * inv),
                          (unsigned int)f2h(rz * inv) | (j << 16));
    mr[slot] = make_uint4(pack2h(rbf[0], rbf[1]), pack2h(rbf[2], rbf[3]),
                          pack2h(rbf[4], rbf[5]), pack2h(rbf[6], rbf[7]));
}

// ---------------------------------------------------------------------------
// Per-edge message math (all static indexing; inlined into both slots).
// h comes packed fp16 in H; rbf pairs in R.
// ---------------------------------------------------------------------------
__device__ __forceinline__ void edge_compute(
    uint2 P0, uint4 P1, unsigned short g28, uint2 H, uint4 R,
    const uint4 wrq[11], float& A0, float (&A1)[3], float (&A2)[9])
{
    const float h0 = h2f_lo(H.x), h1 = h2f_hi(H.x), h2 = h2f_lo(H.y);

    float w[11];
    #pragma unroll
    for (int p = 0; p < 11; ++p)
        w[p] = fdot2u(R.x, wrq[p].x,
               fdot2u(R.y, wrq[p].y,
               fdot2u(R.z, wrq[p].z,
               fdot2u(R.w, wrq[p].w, 0.0f))));

    const float G0 = h2f_lo(P0.x);
    float G1[3];
    G1[0] = h2f_hi(P0.x); G1[1] = h2f_lo(P0.y); G1[2] = h2f_hi(P0.y);
    float G2[9];
    G2[0] = h2f_lo(P1.x); G2[1] = h2f_hi(P1.x);
    G2[2] = h2f_lo(P1.y); G2[3] = h2f_hi(P1.y);
    G2[4] = h2f_lo(P1.z); G2[5] = h2f_hi(P1.z);
    G2[6] = h2f_lo(P1.w); G2[7] = h2f_hi(P1.w);
    G2[8] = __half2float(__ushort_as_half(g28));

    const float hh[3] = {h0, h1, h2};
    const float s1 = G1[0] * h0 + G1[1] * h1 + G1[2] * h2;
    float tt[3];
    #pragma unroll
    for (int a = 0; a < 3; ++a)
        tt[a] = G2[a * 3 + 0] * h0 + G2[a * 3 + 1] * h1 + G2[a * 3 + 2] * h2;
    const float s2 = tt[0] * h0 + tt[1] * h1 + tt[2] * h2;

    A0 += G0 * w[0] + s1 * w[4] + s2 * w[9];
    #pragma unroll
    for (int a = 0; a < 3; ++a)
        A1[a] += (G0 * w[1] + s1 * w[6]) * hh[a] + G1[a] * w[3] + tt[a] * w[8];
    #pragma unroll
    for (int a = 0; a < 3; ++a) {
        float pre = G0 * w[2] * hh[a] + G1[a] * w[5] + tt[a] * w[10];
        #pragma unroll
        for (int b = 0; b < 3; ++b)
            A2[a * 3 + b] += pre * hh[b] + G2[a * 3 + b] * w[7];
    }
}

// ---------------------------------------------------------------------------
// Aggregate kernel v6 (proven 74.5 us): v3 structure, meta 24 B/edge with
// j embedded in mh (mh takes over jord's depth-2 prefetch role). One WAVE64
// per node, lane=(side<<5)|c, 2 slots/side = 4 edges in flight.
// ---------------------------------------------------------------------------
__global__ __launch_bounds__(256) void aggregate_kernel(
    const uint2* __restrict__ t0g, const uint4* __restrict__ t1g,
    const unsigned short* __restrict__ t2g, const unsigned int* __restrict__ wradp,
    const uint2* __restrict__ mh, const uint4* __restrict__ mr,
    const int* __restrict__ offsets,
    float* __restrict__ a0, float* __restrict__ a1, float* __restrict__ a2,
    int N)
{
    const int lane = threadIdx.x & 63;
    const int c = lane & 31;
    const int side = lane >> 5;
    const int n = blockIdx.x * 4 + (threadIdx.x >> 6);
    if (n >= N) return;

    // my channel's radial weights: 11 x dwordx4 (contiguous per lane)
    uint4 wrq[11];
    {
        const uint4* wrv = reinterpret_cast<const uint4*>(wradp) + c * 11;
        #pragma unroll
        for (int p = 0; p < 11; ++p) wrq[p] = wrv[p];
    }

    const int beg = offsets[n], end = offsets[n + 1];
    const int deg = end - beg;

    float A0 = 0.f;
    float A1[3] = {0.f, 0.f, 0.f};
    float A2[9] = {0.f, 0.f, 0.f, 0.f, 0.f, 0.f, 0.f, 0.f, 0.f};

    if (deg > 0) {
        const int last = end - 1;
        int eA = beg + side;     // slot A edges: beg+side, +4, +8, ...
        int eB = eA + 2;         // slot B edges: beg+side+2, +6, ...

        // prologue: load edge data for eA/eB; prefetch mh one level ahead
        uint2 HA, HB, MHA, MHB;
        uint2 P0A, P0B; uint4 P1A, P1B; unsigned short s2A, s2B;
        uint4 RA, RB;
        {
            const int em = min(eA, last);
            HA = mh[em];
            const size_t b = ((size_t)(HA.y >> 16) << 5) + c;
            P0A = t0g[b]; P1A = t1g[b]; s2A = t2g[b];
            RA = mr[em];
            MHA = mh[min(eA + 4, last)];
        }
        {
            const int em = min(eB, last);
            HB = mh[em];
            const size_t b = ((size_t)(HB.y >> 16) << 5) + c;
            P0B = t0g[b]; P1B = t1g[b]; s2B = t2g[b];
            RB = mr[em];
            MHB = mh[min(eB + 4, last)];
        }

        const int M = (deg + 3) >> 2;

#define SLOT_STEP(P0s, P1s, s2s, Hs, Rs, MHs, eS)                           \
        {                                                                   \
            const uint2 P0 = P0s; const uint4 P1 = P1s;                     \
            const unsigned short g28 = s2s;                                 \
            const uint2 Hc = Hs; const uint4 Rc = Rs;                       \
            const bool v = (eS < end);                                      \
            const int eSn = eS + 4;                                         \
            {                                                               \
                const size_t b = ((size_t)(MHs.y >> 16) << 5) + c;          \
                P0s = t0g[b]; P1s = t1g[b]; s2s = t2g[b];                   \
                Rs = mr[min(eSn, last)];                                    \
            }                                                               \
            Hs = MHs;                                                       \
            MHs = mh[min(eSn + 4, last)];                                   \
            if (v) edge_compute(P0, P1, g28, Hc, Rc, wrq, A0, A1, A2);      \
            eS = eSn;                                                       \
        }

        for (int m = 0; m < M; ++m) {
            SLOT_STEP(P0A, P1A, s2A, HA, RA, MHA, eA)
            SLOT_STEP(P0B, P1B, s2B, HB, RB, MHB, eB)
        }
#undef SLOT_STEP
    }

    // combine even/odd partial sums across the two wave halves
    A0 += __shfl_xor(A0, 32, 64);
    #pragma unroll
    for (int a = 0; a < 3; ++a) A1[a] += __shfl_xor(A1[a], 32, 64);
    #pragma unroll
    for (int k = 0; k < 9; ++k) A2[k] += __shfl_xor(A2[k], 32, 64);

    if (side == 0) {
        a0[n * 32 + c] = A0;
        #pragma unroll
        for (int a = 0; a < 3; ++a) a1[n * 96 + a * 32 + c] = A1[a];
        #pragma unroll
        for (int k = 0; k < 9; ++k) a2[n * 288 + k * 32 + c] = A2[k];
    }
}

// ---------------------------------------------------------------------------
// Node kernel (proven): weights read DIRECTLY from global (28.7 KB hot set,
// shared by all blocks via L1/L2; per-lane-contiguous dwordx4). LDS only
// holds the per-block feature tensor -> 26.1 KB -> 6 blocks/CU.
// ---------------------------------------------------------------------------
__global__ __launch_bounds__(256) void node_kernel(
    const float* __restrict__ node0, const float* __restrict__ node1,
    const float* __restrict__ node2, const unsigned short* __restrict__ wswz,
    float* __restrict__ out0, float* __restrict__ out1, float* __restrict__ out2,
    int N)
{
    __shared__ alignas(16) unsigned short feat[NPB * 49 * 32]; // 25.1 KB fp16
    __shared__ alignas(16) float y0s[NPB][32];                 // 1 KB

    const uint4* __restrict__ W4 = reinterpret_cast<const uint4*>(wswz); // m*128 + q*32 + d

    const int g = threadIdx.x >> 5;
    const int lane = threadIdx.x & 31;
    const int n = blockIdx.x * NPB + g;
    const bool active = (n < N);

    if (active) {
        const int c = lane;
        float A0 = out0[n * 32 + c];
        float A1[3], A2[9];
        #pragma unroll
        for (int a = 0; a < 3; ++a) A1[a] = out1[n * 96 + a * 32 + c];   // transposed
        #pragma unroll
        for (int k = 0; k < 9; ++k) A2[k] = out2[n * 288 + k * 32 + c];  // transposed

        unsigned short* F = &feat[g * 49 * 32];
        F[0 * 32 + c] = f2h(A0);
        F[1 * 32 + c] = f2h(A0 * A0);
        F[2 * 32 + c] = f2h(A1[0] * A1[0] + A1[1] * A1[1] + A1[2] * A1[2]);
        float n2 = 0.f;
        #pragma unroll
        for (int k = 0; k < 9; ++k) n2 += A2[k] * A2[k];
        F[3 * 32 + c] = f2h(n2);
        #pragma unroll
        for (int a = 0; a < 3; ++a) {
            F[(4 + a) * 32 + c] = f2h(A1[a]);
            F[(7 + a) * 32 + c] = f2h(A0 * A1[a]);
        }
        #pragma unroll
        for (int b = 0; b < 3; ++b) {  // B5[b] = sum_a a1[a]*a2[a,b]
            float s = A1[0] * A2[0 * 3 + b] + A1[1] * A2[1 * 3 + b] + A1[2] * A2[2 * 3 + b];
            F[(10 + b) * 32 + c] = f2h(s);
        }
        #pragma unroll
        for (int k = 0; k < 9; ++k) {
            F[(13 + k) * 32 + c] = f2h(A2[k]);
            F[(22 + k) * 32 + c] = f2h(A0 * A2[k]);
        }
        #pragma unroll
        for (int a = 0; a < 3; ++a)
            #pragma unroll
            for (int b = 0; b < 3; ++b)
                F[(31 + a * 3 + b) * 32 + c] = f2h(A1[a] * A1[b]);
        #pragma unroll
        for (int a = 0; a < 3; ++a)
            #pragma unroll
            for (int dd = 0; dd < 3; ++dd) { // B7[a,d] = sum_b a2[a,b]*a2[b,d]
                float s = A2[a * 3 + 0] * A2[0 * 3 + dd] + A2[a * 3 + 1] * A2[1 * 3 + dd]
                        + A2[a * 3 + 2] * A2[2 * 3 + dd];
                F[(40 + a * 3 + dd) * 32 + c] = f2h(s);
            }
    }
    __syncthreads();

    const int d = lane;
    float y0v = 0.f;
    float y1v[3] = {0.f, 0.f, 0.f};
    float y2v[9] = {0.f, 0.f, 0.f, 0.f, 0.f, 0.f, 0.f, 0.f, 0.f};

    if (active) {
        const uint4* F4 = reinterpret_cast<const uint4*>(&feat[g * 49 * 32]); // f*4 + q
        for (int q = 0; q < 4; ++q) {
            const int q32d = q * 32 + d;
            acc8h(y0v, W4[0 * 128 + q32d], F4[0 * 4 + q]);
            acc8h(y0v, W4[3 * 128 + q32d], F4[1 * 4 + q]);
            acc8h(y0v, W4[6 * 128 + q32d], F4[2 * 4 + q]);
            acc8h(y0v, W4[9 * 128 + q32d], F4[3 * 4 + q]);
            uint4 wU1 = W4[1 * 128 + q32d];
            uint4 wV1 = W4[4 * 128 + q32d];
            uint4 wV5 = W4[8 * 128 + q32d];
            #pragma unroll
            for (int a = 0; a < 3; ++a) {
                acc8h(y1v[a], wU1, F4[(4 + a) * 4 + q]);
                acc8h(y1v[a], wV1, F4[(7 + a) * 4 + q]);
                acc8h(y1v[a], wV5, F4[(10 + a) * 4 + q]);
            }
            uint4 wU2 = W4[2 * 128 + q32d];
            uint4 wV2 = W4[5 * 128 + q32d];
            uint4 wV4 = W4[7 * 128 + q32d];
            uint4 wV7 = W4[10 * 128 + q32d];
            #pragma unroll
            for (int k = 0; k < 9; ++k) {
                acc8h(y2v[k], wU2, F4[(13 + k) * 4 + q]);
                acc8h(y2v[k], wV2, F4[(22 + k) * 4 + q]);
                acc8h(y2v[k], wV4, F4[(31 + k) * 4 + q]);
                acc8h(y2v[k], wV7, F4[(40 + k) * 4 + q]);
            }
        }
        y0s[g][d] = y0v;
    }
    __syncthreads();

    if (!active) return;

    float t0 = 0.f, t1 = 0.f, t2 = 0.f;
    {
        const float4* Y4 = reinterpret_cast<const float4*>(y0s[g]);
        #pragma unroll
        for (int q = 0; q < 4; ++q) {
            const int q32d = q * 32 + d;
            float4 ya = Y4[2 * q], yb = Y4[2 * q + 1];
            acc8fh(t0, W4[11 * 128 + q32d], ya, yb);
            acc8fh(t1, W4[12 * 128 + q32d], ya, yb);
            acc8fh(t2, W4[13 * 128 + q32d], ya, yb);
        }
    }
    float s0 = t0 / (1.0f + __expf(-t0));
    float s1 = t1 / (1.0f + __expf(-t1));
    float s2 = t2 / (1.0f + __expf(-t2));

    out0[n * 32 + d] = node0[n * 32 + d] + s0;
    #pragma unroll
    for (int a = 0; a < 3; ++a)
        out1[n * 96 + d * 3 + a] = node1[n * 96 + d * 3 + a] + y1v[a] * s1;
    #pragma unroll
    for (int k = 0; k < 9; ++k)
        out2[n * 288 + d * 9 + k] = node2[n * 288 + d * 9 + k] + y2v[k] * s2;
}

extern "C" void kernel_launch(void* const* d_in, const int* in_sizes, int n_in,
                              void* d_out, int out_size, void* d_ws, size_t ws_size,
                              hipStream_t stream)
{
    const float* node0 = (const float*)d_in[0];
    const float* node1 = (const float*)d_in[1];
    const float* node2 = (const float*)d_in[2];
    const float* rij   = (const float*)d_in[3];
    const float* Wrad  = (const float*)d_in[4];
    const float* U     = (const float*)d_in[5];
    const float* V     = (const float*)d_in[6];
    const float* Wg    = (const float*)d_in[7];
    const int* idx_i   = (const int*)d_in[8];
    const int* idx_j   = (const int*)d_in[9];

    const int N = in_sizes[0] / 32;
    const int E = in_sizes[3] / 3;

    float* out0 = (float*)d_out;
    float* out1 = out0 + (size_t)N * 32;
    float* out2 = out1 + (size_t)N * 96;

    // workspace carve-up (64B aligned regions)
    size_t off = 0;
    auto walloc = [&](size_t bytes) -> void* {
        off = (off + 63) & ~(size_t)63;
        void* p = (char*)d_ws + off;
        off += bytes;
        return p;
    };
    int*    cursor    = (int*)   walloc((size_t)N * 4);
    int*    offsets   = (int*)   walloc((size_t)(N + 1) * 4);
    int*    blocksums = (int*)   walloc(64 * 4);
    int*    bases     = (int*)   walloc(64 * 4);
    uint2*  mh        = (uint2*) walloc((size_t)E * sizeof(uint2));        // 33.3 MB
    uint4*  mr        = (uint4*) walloc((size_t)E * sizeof(uint4));        // 66.6 MB
    uint2*  t0g       = (uint2*) walloc((size_t)N * 32 * sizeof(uint2));   // 5.1 MB
    uint4*  t1g       = (uint4*) walloc((size_t)N * 32 * sizeof(uint4));   // 10.2 MB
    unsigned short* t2g = (unsigned short*)walloc((size_t)N * 32 * 2);     // 1.3 MB
    unsigned short* wswz = (unsigned short*)walloc(14 * 1024 * 2);
    unsigned int*  wradp = (unsigned int*)walloc(11 * 4 * 32 * 4);
    (void)ws_size;

    const int nb = (N + 1023) / 1024;
    const int TB = (N + 7) / 8;
    const int HB = (E + 255) / 256;

    hipMemsetAsync(cursor, 0, (size_t)N * sizeof(int), stream);

    prep_kernel<<<dim3(TB + 62 + HB), dim3(256), 0, stream>>>(
        node0, node1, node2, U, V, Wg, Wrad, idx_i, cursor,
        t0g, t1g, t2g, wswz, wradp, N, E, TB);
    scan_reduce_kernel<<<dim3(nb), dim3(256), 0, stream>>>(cursor, blocksums, N);
    scan_top_kernel<<<dim3(1), dim3(64), 0, stream>>>(blocksums, bases, offsets, nb, N);
    scan_write_kernel<<<dim3(nb), dim3(256), 0, stream>>>(cursor, bases, offsets, N);
    scatter_meta_kernel<<<dim3((E + 255) / 256), dim3(256), 0, stream>>>(
        idx_i, idx_j, rij, cursor, mh, mr, E);

    aggregate_kernel<<<dim3((N + 3) / 4), dim3(256), 0, stream>>>(
        t0g, t1g, t2g, wradp, mh, mr, offsets, out0, out1, out2, N);

    node_kernel<<<dim3((N + NPB - 1) / NPB), dim3(256), 0, stream>>>(
        node0, node1, node2, wswz, out0, out1, out2, N);
}